// Round 13
// baseline (190.656 us; speedup 1.0000x reference)
//
#include <hip/hip_runtime.h>

#define B_    16
#define T_    2500
#define X_    512
#define WTILE 16                  // output cols per wave
#define NXT   (X_ / WTILE)        // 32
#define SEGS  6
#define SEGR  420                 // 6*420 = 2520 >= 2500
#define NWAVE (B_ * SEGS * NXT)   // 3072 waves
#define NBLK  (NWAVE / 4)         // 768 blocks (4 indep waves each)
#define RST   144                 // ring col stride bytes (2-way banks, 16B-align ok)

typedef __attribute__((ext_vector_type(4))) float f32x4;

// Round-13: barrier-free wave-private pipeline (diagnosis: r9-r12 were
// LDS-pipe-bound, ~320 DS ops/CU/period ~= 70-85% LDS busy; schedule levers
// were all null because they don't cut DS ops).
//  - one wave owns a 16-col x T-seg tile; NO __syncthreads anywhere
//  - PB deleted: each lane global-loads exactly its xconv B-fragment cols
//    (row ln16, cols soff+8g..+7; 2x float4 per input), products+fp8 pack in
//    registers -> DS ops/wave-period drop 40 -> 25 (5 ring-W + 20 tconv-R)
//  - per-wave fp8 ring [5][16 col][128 rows], col stride 144B (bank spread);
//    ring row = absolute chunk row mod 128 (8-chunk window, exact)
//  - all MFMA fragment conventions and the DPP 4x4 transpose are r4-r12
//    verified, carried verbatim; tconv = 4x verified 16x16x32 fp8 MFMA
//  - waves of one block = adjacent x-tiles (halo shared in L1/L2); XCD swizzle
__global__ __launch_bounds__(256, 3) void coh13(const float* __restrict__ xg,
                                                const float* __restrict__ yg,
                                                float* __restrict__ partial)
{
    __shared__ __align__(16) uchar XS[4][5][WTILE][RST];   // 46080 B

    const int tid  = threadIdx.x;
    const int w    = tid >> 6;
    const int lane = tid & 63;
    const int g    = lane >> 4;
    const int ln16 = lane & 15;

    // ---- XCD-aware bijective swizzle (768 % 8 == 0) ----
    const int bid = blockIdx.x;
    const int wid = (bid & 7) * (NBLK / 8) + (bid >> 3);
    const int gwv = wid * 4 + w;            // global wave id; block waves = adjacent xt
    const int xt   = gwv & (NXT - 1);
    const int rest = gwv >> 5;              // 0..95
    const int seg  = rest % SEGS;
    const int b    = rest / SEGS;

    const int x0    = xt * WTILE;
    const int soff  = x0 - 8;               // staged cols soff..soff+31; A[m][k]=kx[k-m-3]
    const int t0    = seg * SEGR;
    const int t_end = min(t0 + SEGR, T_);
    const int nm    = (t_end - t0 + 15) >> 4;
    const int pend  = nm + 6;

    // ---- normalization sums (registers, one-time) ----
    float ksx = 0.f, kst = 0.f;
#pragma unroll 1
    for (int i = 0; i < 11; ++i)  { float d = (float)(i - 5);  ksx += expf(-d * d * (1.f / 242.f)); }
#pragma unroll 1
    for (int i = 0; i < 101; ++i) { float d = (float)(i - 50); kst += expf(-d * d * (1.f / 882.f)); }
    const float scx = 16.f / ksx;
    const float sct = 16.f / kst;

    // ---- A_x: A[m][k] = kx[k-m-3]*16 fp8; lane m=ln16, k = 8g+sl (r4 convention) ----
    long a_x;
    {
        float vv[8];
#pragma unroll
        for (int sl = 0; sl < 8; ++sl) {
            int idx = 8 * g + sl - ln16 - 3;
            float d = (float)(idx - 5);
            vv[sl] = (idx >= 0 && idx <= 10) ? expf(-d * d * (1.f / 242.f)) * scx : 0.f;
        }
        int lo = __builtin_amdgcn_cvt_pk_fp8_f32(vv[0], vv[1], 0, false);
        lo     = __builtin_amdgcn_cvt_pk_fp8_f32(vv[2], vv[3], lo, true);
        int hi = __builtin_amdgcn_cvt_pk_fp8_f32(vv[4], vv[5], 0, false);
        hi     = __builtin_amdgcn_cvt_pk_fp8_f32(vv[6], vv[7], hi, true);
        a_x = (long)(((unsigned long long)(unsigned)hi << 32) | (unsigned)lo);
    }
    // ---- A_t[c]: A[m][k] = kt[k-m-6]*16 fp8; k = 32c+8g+sl (r4 convention) ----
    long a_t[4];
#pragma unroll
    for (int c = 0; c < 4; ++c) {
        float vv[8];
#pragma unroll
        for (int sl = 0; sl < 8; ++sl) {
            int idx = 32 * c + 8 * g + sl - ln16 - 6;
            float d = (float)(idx - 50);
            vv[sl] = (idx >= 0 && idx <= 100) ? expf(-d * d * (1.f / 882.f)) * sct : 0.f;
        }
        int lo = __builtin_amdgcn_cvt_pk_fp8_f32(vv[0], vv[1], 0, false);
        lo     = __builtin_amdgcn_cvt_pk_fp8_f32(vv[2], vv[3], lo, true);
        int hi = __builtin_amdgcn_cvt_pk_fp8_f32(vv[4], vv[5], 0, false);
        hi     = __builtin_amdgcn_cvt_pk_fp8_f32(vv[6], vv[7], hi, true);
        a_t[c] = (long)(((unsigned long long)(unsigned)hi << 32) | (unsigned)lo);
    }

    // ---- DPP 4x4 byte-transpose constants (verified r5-r12) ----
    const uint sel1 = (ln16 & 1) ? 0x07030602u : 0x01050004u;
    const uint sel2 = (ln16 & 2) ? 0x07060302u : 0x01000504u;
    const int  cidx = ((ln16 & 1) << 1) | ((ln16 >> 1) & 1);
    const int  wcol = 4 * g + cidx;        // ring col this lane writes
    const int  rq   = ln16 & 12;           // row-quad byte offset within chunk

    const float* xb = xg + (size_t)b * T_ * X_;
    const float* yb = yg + (size_t)b * T_ * X_;
    const int  c0  = soff + 8 * g;
    const int  c1  = c0 + 4;
    const bool ok0 = (c0 >= 0) && (c0 + 3 < X_);
    const bool ok1 = (c1 >= 0) && (c1 + 3 < X_);
    const float4 z4 = make_float4(0.f, 0.f, 0.f, 0.f);

    uchar* ring = &XS[w][0][0][0];         // [f][col][RST]

    float4 xv0, xv1, yv0, yv1;
    auto issue = [&](int p) {
        int tau = t0 - 56 + 16 * p + ln16;  // this lane's staged row for chunk p
        bool rok = (tau >= 0) && (tau < T_);
        const float* xr = xb + (size_t)tau * X_;
        const float* yr = yb + (size_t)tau * X_;
        xv0 = (rok && ok0) ? *(const float4*)(xr + c0) : z4;
        xv1 = (rok && ok1) ? *(const float4*)(xr + c1) : z4;
        yv0 = (rok && ok0) ? *(const float4*)(yr + c0) : z4;
        yv1 = (rok && ok1) ? *(const float4*)(yr + c1) : z4;
    };
    issue(0);

    float local = 0.f;

    for (int p = 0; p <= pend; ++p) {
        // ---- products of chunk p, in registers (lane = (row ln16, cols 8g..8g+7)) ----
        float xa[8] = {xv0.x, xv0.y, xv0.z, xv0.w, xv1.x, xv1.y, xv1.z, xv1.w};
        float ya[8] = {yv0.x, yv0.y, yv0.z, yv0.w, yv1.x, yv1.y, yv1.z, yv1.w};
        long bf[5];
        {
            float p2[8], p3[8], p4[8];
#pragma unroll
            for (int i = 0; i < 8; ++i) { p2[i] = xa[i] * xa[i]; p3[i] = ya[i] * ya[i]; p4[i] = xa[i] * ya[i]; }
            auto pack8 = [](const float* v) -> long {
                int lo = __builtin_amdgcn_cvt_pk_fp8_f32(v[0], v[1], 0, false);
                lo     = __builtin_amdgcn_cvt_pk_fp8_f32(v[2], v[3], lo, true);
                int hi = __builtin_amdgcn_cvt_pk_fp8_f32(v[4], v[5], 0, false);
                hi     = __builtin_amdgcn_cvt_pk_fp8_f32(v[6], v[7], hi, true);
                return (long)(((unsigned long long)(unsigned)hi << 32) | (unsigned)lo);
            };
            bf[0] = pack8(xa); bf[1] = pack8(ya); bf[2] = pack8(p2); bf[3] = pack8(p3); bf[4] = pack8(p4);
        }

        // ---- xconv MFMA -> DPP transpose -> ring (rows (16p + rq) mod 128) ----
        const int roff = (p << 4) & 127;
#pragma unroll
        for (int f = 0; f < 5; ++f) {
            f32x4 z; z[0] = 0.f; z[1] = 0.f; z[2] = 0.f; z[3] = 0.f;
            f32x4 d = __builtin_amdgcn_mfma_f32_16x16x32_fp8_fp8(a_x, bf[f], z, 0, 0, 0);
            int pk = __builtin_amdgcn_cvt_pk_fp8_f32(d[0], d[1], 0, false);
            pk     = __builtin_amdgcn_cvt_pk_fp8_f32(d[2], d[3], pk, true);
            uint pkc   = (uint)pk;
            uint part1 = (uint)__builtin_amdgcn_update_dpp(0, (int)pkc, 177, 0xF, 0xF, true);
            uint s1v   = __builtin_amdgcn_perm(pkc, part1, sel1);
            uint part2 = (uint)__builtin_amdgcn_update_dpp(0, (int)s1v, 78, 0xF, 0xF, true);
            uint Tt    = __builtin_amdgcn_perm(s1v, part2, sel2);
            *(uint*)(ring + (f * WTILE + wcol) * RST + roff + rq) = Tt;
        }

        // ---- prefetch next chunk's loads (fly under tconv) ----
        if (p < pend) issue(p + 1);

        // ---- tconv strip m = p-7 (ring holds chunks p-7..p exactly) ----
        if (p >= 7) {
            const int m = p - 7;
            long br[4][5];
#pragma unroll
            for (int c = 0; c < 4; ++c) {
                const int off = ((m << 4) + (c << 5) + (g << 3)) & 127;
#pragma unroll
                for (int f = 0; f < 5; ++f)
                    br[c][f] = *(const long*)(ring + (f * WTILE + ln16) * RST + off);
            }
            f32x4 acc[5];
#pragma unroll
            for (int f = 0; f < 5; ++f) { acc[f][0] = 0.f; acc[f][1] = 0.f; acc[f][2] = 0.f; acc[f][3] = 0.f; }
#pragma unroll
            for (int c = 0; c < 4; ++c)
#pragma unroll
                for (int f = 0; f < 5; ++f)
                    acc[f] = __builtin_amdgcn_mfma_f32_16x16x32_fp8_fp8(a_t[c], br[c][f], acc[f], 0, 0, 0);

            // ---- pointwise coherence (acc = 256 x field; eps' = 1e-9*256^2) ----
            const float s_ = 1.f / 256.f;
            const int tb = t0 + 16 * m + 4 * g;
            if (tb + 3 < t_end) {
#pragma unroll
                for (int r = 0; r < 4; ++r) {
                    float a0 = acc[0][r], a1 = acc[1][r];
                    float sa0 = a0 * s_, sa1 = a1 * s_;
                    float cov = fmaf(-sa0, a1, acc[4][r]);
                    float vx  = fmaf(-sa0, a0, acc[2][r]);
                    float vy  = fmaf(-sa1, a1, acc[3][r]);
                    local += 1.0f - cov * rsqrtf(fmaf(vx, vy, 6.5536e-5f));
                }
            } else {
#pragma unroll
                for (int r = 0; r < 4; ++r) {
                    if (tb + r < t_end) {
                        float a0 = acc[0][r], a1 = acc[1][r];
                        float sa0 = a0 * s_, sa1 = a1 * s_;
                        float cov = fmaf(-sa0, a1, acc[4][r]);
                        float vx  = fmaf(-sa0, a0, acc[2][r]);
                        float vy  = fmaf(-sa1, a1, acc[3][r]);
                        local += 1.0f - cov * rsqrtf(fmaf(vx, vy, 6.5536e-5f));
                    }
                }
            }
        }
    }

    // ---- wave reduction -> one partial per wave (no cross-wave sync needed) ----
#pragma unroll
    for (int off = 32; off >= 1; off >>= 1) local += __shfl_down(local, off);
    if (lane == 0) partial[gwv] = local;
}

__global__ __launch_bounds__(256) void coh_reduce(const float* __restrict__ partial,
                                                  float* __restrict__ out) {
    __shared__ float wred[4];
    const int tid = threadIdx.x;
    float s = 0.0f;
    for (int i = tid; i < NWAVE; i += 256) s += partial[i];
#pragma unroll
    for (int off = 32; off >= 1; off >>= 1) s += __shfl_down(s, off);
    if ((tid & 63) == 0) wred[tid >> 6] = s;
    __syncthreads();
    if (tid == 0)
        out[0] = (wred[0] + wred[1] + wred[2] + wred[3]) *
                 (1.0f / ((float)B_ * (float)T_ * (float)X_));
}

extern "C" void kernel_launch(void* const* d_in, const int* in_sizes, int n_in,
                              void* d_out, int out_size, void* d_ws, size_t ws_size,
                              hipStream_t stream) {
    const float* x = (const float*)d_in[0];
    const float* y = (const float*)d_in[1];
    float* out = (float*)d_out;
    float* partial = (float*)d_ws;   // NWAVE floats = 12 KB

    coh13<<<dim3(NBLK), 256, 0, stream>>>(x, y, partial);
    coh_reduce<<<1, 256, 0, stream>>>(partial, out);
}

// Round 14
// 100.648 us; speedup vs baseline: 1.8943x; 1.8943x over previous
//
#include <hip/hip_runtime.h>

#define B_   16
#define T_   2500
#define X_   512
#define XT   32
#define SEGS 3
#define SEGR 848
#define NSX  (X_ / XT)            // 16
#define NBLK (B_ * SEGS * NSX)    // 768 = 3 blocks/CU exactly
#define RING 24

typedef __attribute__((ext_vector_type(4))) float f32x4;

// lgkm-only barrier (verified r9): LDS producer->consumer visibility without
// draining vmcnt; prefetched global loads stay in flight across it.
__device__ __forceinline__ void barrier_lgkm() {
    asm volatile("s_waitcnt lgkmcnt(0)\n\ts_barrier" ::: "memory");
}

// Round-14 = r9's two-role pipeline with HALF the barrier events:
//  - 2 chunks (32 rows) per barrier period; producers xconv 2 staged chunks,
//    stage 2 new ones, prefetch 2; consumers run 2 tconv strips. Barriers/blk
//    49 -> 33 (r13 falsified LDS-throughput; r9's residual = barrier skew).
//  - r12's private-row xconv (refcheck-passed): wave reads only PB rows it
//    wrote (rows 16e+8*p01+..) -> single PB valid across the 2-chunk period.
//  - PB keeps 72-B row stride (r12's regression was its 64-B stride).
//  - RING=24, lag-6: consumer reads groups <= 4p-7, producer writes 4p-4..
//    4p-1 -> disjoint. Ring f-stride padded to 33 (slot stride !≡ 0 mod 32
//    banks -> tconv read conflicts halved).
//  - grid 768 = 3 blocks/CU exact (as r9's 1024=4/CU); SEGS=3 cuts T-halo.
//  - tables in registers (r10-verified); XCD swizzle (768%8==0); role mixing.
__global__ __launch_bounds__(256, 3) void coh14(const float* __restrict__ xg,
                                                const float* __restrict__ yg,
                                                float* __restrict__ partial)
{
    __shared__ unsigned long long XS[RING][5][33];  // 31680 B fp8 ring; entry = 8 t-rows of one (f,col)
    __shared__ unsigned long long PB[5][32][9];     // 11520 B fp8 products, 2 chunks; byte j = staged col j
    __shared__ float wred[4];

    const int tid  = threadIdx.x;
    const int lane = tid & 63;
    const int w    = tid >> 6;
    const int g    = lane >> 4;
    const int ln16 = lane & 15;
    const int p01  = w & 1;

    // ---- XCD-aware bijective block swizzle (768 blocks, 8 XCDs) ----
    const int bid = blockIdx.x;
    const int wid = (bid & 7) * (NBLK / 8) + (bid >> 3);
    const int xt   = wid & 15;
    const int rest = wid >> 4;          // 0..47
    const int seg  = rest % SEGS;
    const int b    = rest / SEGS;

    const int pair = ((w >> 1) ^ wid) & 1;   // role-mixed across co-resident blocks

    const int x0    = xt * XT;
    const int t0    = seg * SEGR;
    const int t_end = min(t0 + SEGR, T_);
    const int nm    = (t_end - t0 + 15) >> 4;     // strips (53/53/51)
    const int pmax  = 6 + ((nm - 1) >> 1);

    const float* xb = xg + (size_t)b * T_ * X_;
    const float* yb = yg + (size_t)b * T_ * X_;

    float local = 0.f;

    if (pair == 0) {
        // ===================== producer =====================
        float ksx = 0.f;
#pragma unroll 1
        for (int i = 0; i < 11; ++i) { float d = (float)(i - 5); ksx += expf(-d * d * (1.f / 242.f)); }
        const float scx = 16.f / ksx;
        // A_x[m][k] = kx[k-m-3]*16 fp8; m = ln16, k = 8g+sl (r4-verified convention)
        long a_x;
        {
            float vv[8];
#pragma unroll
            for (int sl = 0; sl < 8; ++sl) {
                int idx = 8 * g + sl - ln16 - 3;
                float d = (float)(idx - 5);
                vv[sl] = (idx >= 0 && idx <= 10) ? expf(-d * d * (1.f / 242.f)) * scx : 0.f;
            }
            int lo = __builtin_amdgcn_cvt_pk_fp8_f32(vv[0], vv[1], 0, false);
            lo     = __builtin_amdgcn_cvt_pk_fp8_f32(vv[2], vv[3], lo, true);
            int hi = __builtin_amdgcn_cvt_pk_fp8_f32(vv[4], vv[5], 0, false);
            hi     = __builtin_amdgcn_cvt_pk_fp8_f32(vv[6], vv[7], hi, true);
            a_x = (long)(((unsigned long long)(unsigned)hi << 32) | (unsigned)lo);
        }
        // DPP 4x4 byte-transpose constants (verified r5-r12)
        const uint sel1  = (ln16 & 1) ? 0x07030602u : 0x01050004u;
        const uint sel2  = (ln16 & 2) ? 0x07060302u : 0x01000504u;
        const int  cidx  = ((ln16 & 1) << 1) | ((ln16 >> 1) & 1);
        const int  abyte = (ln16 & 4);
        const int  hh    = ln16 >> 3;              // col-half (r12 n-mapping)
        const int  prow  = 8 * p01 + (ln16 & 7);   // own PB row (within a chunk)

        const int  gcol  = x0 - 16 + 4 * ln16;
        const bool colOK = (gcol >= 0) && (gcol < X_);
        const float* xpl = xb + gcol;
        const float* ypl = yb + gcol;
        const float4 z4  = make_float4(0.f, 0.f, 0.f, 0.f);

        float4 xv[2][2], yv[2][2];
        auto issue = [&](int c, int e) {
            const int rowlo = t0 - 56 + 16 * c;
            if (rowlo >= 0 && rowlo + 15 < T_) {          // fast: rows in-bounds
#pragma unroll
                for (int s = 0; s < 2; ++s) {
                    int grow = rowlo + 8 * p01 + 4 * s + g;
                    xv[e][s] = colOK ? *(const float4*)(xpl + (size_t)grow * X_) : z4;
                    yv[e][s] = colOK ? *(const float4*)(ypl + (size_t)grow * X_) : z4;
                }
            } else {                                       // guarded (seg edges)
#pragma unroll
                for (int s = 0; s < 2; ++s) {
                    int grow = rowlo + 8 * p01 + 4 * s + g;
                    bool ok = colOK && (grow >= 0) && (grow < T_);
                    xv[e][s] = ok ? *(const float4*)(xpl + (size_t)grow * X_) : z4;
                    yv[e][s] = ok ? *(const float4*)(ypl + (size_t)grow * X_) : z4;
                }
            }
        };
        issue(0, 0); issue(1, 1);   // prologue: chunks 0,1

        int wb = 20;   // (4p-4) mod 24
        for (int p = 0; p <= pmax; ++p) {
            // ---- xconv of chunks 2(p-1), 2(p-1)+1 -> ring slots wb+2e+p01 ----
#pragma unroll
            for (int e = 0; e < 2; ++e) {
                const int c = 2 * (p - 1) + e;
                if (p >= 1 && c <= nm + 6) {
                    const int u = wb + 2 * e + p01;        // wb in {0,4,..,20} -> u <= 23
#pragma unroll
                    for (int f = 0; f < 5; ++f) {
                        long bfrag = (long)PB[f][(e << 4) + prow][1 + 2 * hh + g];
                        f32x4 z; z[0] = 0.f; z[1] = 0.f; z[2] = 0.f; z[3] = 0.f;
                        f32x4 d = __builtin_amdgcn_mfma_f32_16x16x32_fp8_fp8(a_x, bfrag, z, 0, 0, 0);
                        int pk = __builtin_amdgcn_cvt_pk_fp8_f32(d[0], d[1], 0, false);
                        pk     = __builtin_amdgcn_cvt_pk_fp8_f32(d[2], d[3], pk, true);
                        uint pkc   = (uint)pk;
                        uint part1 = (uint)__builtin_amdgcn_update_dpp(0, (int)pkc, 177, 0xF, 0xF, true);
                        uint s1v   = __builtin_amdgcn_perm(pkc, part1, sel1);
                        uint part2 = (uint)__builtin_amdgcn_update_dpp(0, (int)s1v, 78, 0xF, 0xF, true);
                        uint Tt    = __builtin_amdgcn_perm(s1v, part2, sel2);
                        *(uint*)((uchar*)&XS[u][f][16 * hh + 4 * g + cidx] + abyte) = Tt;
                    }
                }
            }
            // ---- products of chunks 2p, 2p+1 -> own PB rows (consume prefetch) ----
#pragma unroll
            for (int e = 0; e < 2; ++e) {
                const int c = 2 * p + e;
                if (c <= nm + 6) {
#pragma unroll
                    for (int s = 0; s < 2; ++s) {
                        int rrs = (e << 4) + 8 * p01 + 4 * s + g;
                        float4 X = xv[e][s], Y = yv[e][s];
                        int q0 = __builtin_amdgcn_cvt_pk_fp8_f32(X.x, X.y, 0, false);
                        q0     = __builtin_amdgcn_cvt_pk_fp8_f32(X.z, X.w, q0, true);
                        int q1 = __builtin_amdgcn_cvt_pk_fp8_f32(Y.x, Y.y, 0, false);
                        q1     = __builtin_amdgcn_cvt_pk_fp8_f32(Y.z, Y.w, q1, true);
                        int q2 = __builtin_amdgcn_cvt_pk_fp8_f32(X.x * X.x, X.y * X.y, 0, false);
                        q2     = __builtin_amdgcn_cvt_pk_fp8_f32(X.z * X.z, X.w * X.w, q2, true);
                        int q3 = __builtin_amdgcn_cvt_pk_fp8_f32(Y.x * Y.x, Y.y * Y.y, 0, false);
                        q3     = __builtin_amdgcn_cvt_pk_fp8_f32(Y.z * Y.z, Y.w * Y.w, q3, true);
                        int q4 = __builtin_amdgcn_cvt_pk_fp8_f32(X.x * Y.x, X.y * Y.y, 0, false);
                        q4     = __builtin_amdgcn_cvt_pk_fp8_f32(X.z * Y.z, X.w * Y.w, q4, true);
                        *(uint*)((uchar*)&PB[0][rrs][0] + 4 * ln16) = (uint)q0;
                        *(uint*)((uchar*)&PB[1][rrs][0] + 4 * ln16) = (uint)q1;
                        *(uint*)((uchar*)&PB[2][rrs][0] + 4 * ln16) = (uint)q2;
                        *(uint*)((uchar*)&PB[3][rrs][0] + 4 * ln16) = (uint)q3;
                        *(uint*)((uchar*)&PB[4][rrs][0] + 4 * ln16) = (uint)q4;
                    }
                }
            }
            // ---- prefetch chunks 2p+2, 2p+3 (fly across the raw barrier) ----
#pragma unroll
            for (int e = 0; e < 2; ++e) {
                const int c = 2 * p + 2 + e;
                if (c <= nm + 6) issue(c, e);
            }
            barrier_lgkm();
            wb += 4; if (wb >= RING) wb -= RING;
        }
    } else {
        // ===================== consumer =====================
        float kst = 0.f;
#pragma unroll 1
        for (int i = 0; i < 101; ++i) { float d = (float)(i - 50); kst += expf(-d * d * (1.f / 882.f)); }
        const float sct = 16.f / kst;
        // A_t[c][m][k] = kt[32c+k-m-6]*16 fp8 (r4-verified convention)
        long a_t[4];
#pragma unroll
        for (int c = 0; c < 4; ++c) {
            float vv[8];
#pragma unroll
            for (int sl = 0; sl < 8; ++sl) {
                int idx = 32 * c + 8 * g + sl - ln16 - 6;
                float d = (float)(idx - 50);
                vv[sl] = (idx >= 0 && idx <= 100) ? expf(-d * d * (1.f / 882.f)) * sct : 0.f;
            }
            int lo = __builtin_amdgcn_cvt_pk_fp8_f32(vv[0], vv[1], 0, false);
            lo     = __builtin_amdgcn_cvt_pk_fp8_f32(vv[2], vv[3], lo, true);
            int hi = __builtin_amdgcn_cvt_pk_fp8_f32(vv[4], vv[5], 0, false);
            hi     = __builtin_amdgcn_cvt_pk_fp8_f32(vv[6], vv[7], hi, true);
            a_t[c] = (long)(((unsigned long long)(unsigned)hi << 32) | (unsigned)lo);
        }

        int cb = 0;   // (4(p-6)) mod 24  (== 4p mod 24)
        for (int p = 0; p <= pmax; ++p) {
            if (p >= 6) {
#pragma unroll
                for (int e = 0; e < 2; ++e) {
                    const int m = 2 * (p - 6) + e;
                    if (m < nm) {
                        // pre-gather 20 fragments (static indices), one lgkm wait
                        long bf0[5], bf1[5], bf2[5], bf3[5];
                        {
                            const int base = cb + 2 * e;
                            int u0 = base + g;      if (u0 >= RING) u0 -= RING;
                            int u1 = base + 4 + g;  if (u1 >= RING) u1 -= RING;
                            int u2 = base + 8 + g;  if (u2 >= RING) u2 -= RING;
                            int u3 = base + 12 + g; if (u3 >= RING) u3 -= RING;
                            const int nn = 16 * p01 + ln16;
#pragma unroll
                            for (int f = 0; f < 5; ++f) bf0[f] = (long)XS[u0][f][nn];
#pragma unroll
                            for (int f = 0; f < 5; ++f) bf1[f] = (long)XS[u1][f][nn];
#pragma unroll
                            for (int f = 0; f < 5; ++f) bf2[f] = (long)XS[u2][f][nn];
#pragma unroll
                            for (int f = 0; f < 5; ++f) bf3[f] = (long)XS[u3][f][nn];
                        }
                        f32x4 acc[5];
#pragma unroll
                        for (int f = 0; f < 5; ++f) { acc[f][0] = 0.f; acc[f][1] = 0.f; acc[f][2] = 0.f; acc[f][3] = 0.f; }
#pragma unroll
                        for (int f = 0; f < 5; ++f) acc[f] = __builtin_amdgcn_mfma_f32_16x16x32_fp8_fp8(a_t[0], bf0[f], acc[f], 0, 0, 0);
#pragma unroll
                        for (int f = 0; f < 5; ++f) acc[f] = __builtin_amdgcn_mfma_f32_16x16x32_fp8_fp8(a_t[1], bf1[f], acc[f], 0, 0, 0);
#pragma unroll
                        for (int f = 0; f < 5; ++f) acc[f] = __builtin_amdgcn_mfma_f32_16x16x32_fp8_fp8(a_t[2], bf2[f], acc[f], 0, 0, 0);
#pragma unroll
                        for (int f = 0; f < 5; ++f) acc[f] = __builtin_amdgcn_mfma_f32_16x16x32_fp8_fp8(a_t[3], bf3[f], acc[f], 0, 0, 0);

                        const float s_ = 1.f / 256.f;   // undo kt(16)*kx(16) scaling
                        if (16 * m + 15 < t_end - t0) { // fast: whole strip valid
#pragma unroll
                            for (int r = 0; r < 4; ++r) {
                                float a0 = acc[0][r], a1 = acc[1][r];
                                float sa0 = a0 * s_, sa1 = a1 * s_;
                                float cov = fmaf(-sa0, a1, acc[4][r]);
                                float vx  = fmaf(-sa0, a0, acc[2][r]);
                                float vy  = fmaf(-sa1, a1, acc[3][r]);
                                local += 1.0f - cov * rsqrtf(fmaf(vx, vy, 6.5536e-5f));
                            }
                        } else {                         // guarded (last strip, seg 2)
#pragma unroll
                            for (int r = 0; r < 4; ++r) {
                                int t = t0 + 16 * m + 4 * g + r;
                                if (t < t_end) {
                                    float a0 = acc[0][r], a1 = acc[1][r];
                                    float sa0 = a0 * s_, sa1 = a1 * s_;
                                    float cov = fmaf(-sa0, a1, acc[4][r]);
                                    float vx  = fmaf(-sa0, a0, acc[2][r]);
                                    float vy  = fmaf(-sa1, a1, acc[3][r]);
                                    local += 1.0f - cov * rsqrtf(fmaf(vx, vy, 6.5536e-5f));
                                }
                            }
                        }
                    }
                }
            }
            barrier_lgkm();
            cb += 4; if (cb >= RING) cb -= RING;
        }
    }

    // ---- block reduction ----
#pragma unroll
    for (int off = 32; off >= 1; off >>= 1) local += __shfl_down(local, off);
    if ((tid & 63) == 0) wred[tid >> 6] = local;
    __syncthreads();
    if (tid == 0)
        partial[wid] = wred[0] + wred[1] + wred[2] + wred[3];
}

__global__ __launch_bounds__(256) void coh_reduce(const float* __restrict__ partial,
                                                  float* __restrict__ out) {
    __shared__ float wred[4];
    const int tid = threadIdx.x;
    float s = 0.0f;
    for (int i = tid; i < NBLK; i += 256) s += partial[i];
#pragma unroll
    for (int off = 32; off >= 1; off >>= 1) s += __shfl_down(s, off);
    if ((tid & 63) == 0) wred[tid >> 6] = s;
    __syncthreads();
    if (tid == 0)
        out[0] = (wred[0] + wred[1] + wred[2] + wred[3]) *
                 (1.0f / ((float)B_ * (float)T_ * (float)X_));
}

extern "C" void kernel_launch(void* const* d_in, const int* in_sizes, int n_in,
                              void* d_out, int out_size, void* d_ws, size_t ws_size,
                              hipStream_t stream) {
    const float* x = (const float*)d_in[0];
    const float* y = (const float*)d_in[1];
    float* out = (float*)d_out;
    float* partial = (float*)d_ws;   // NBLK floats = 3 KB

    coh14<<<dim3(NBLK), 256, 0, stream>>>(x, y, partial);
    coh_reduce<<<1, 256, 0, stream>>>(partial, out);
}